// Round 4
// baseline (589.034 us; speedup 1.0000x reference)
//
#include <hip/hip_runtime.h>
#include <hip/hip_bf16.h>
#include <stdint.h>
#include <stddef.h>

#define Bd  4
#define Sd  1024
#define Hd  1024
#define NHd 16
#define DKd 64
#define SCALEF 0.125f
#define NEGV  -9.0e15f
#define L2E   1.4426950408889634f

typedef __attribute__((ext_vector_type(8))) short bfrag;   // 8 bf16 = 4 VGPRs (MFMA A/B)
typedef __attribute__((ext_vector_type(4))) float facc;    // 4 fp32 (MFMA C/D)

typedef __attribute__((address_space(1))) const unsigned int ga_u32;
typedef __attribute__((address_space(3))) unsigned int ls_u32;

__device__ __forceinline__ void gload_lds16(const void* g, void* l) {
  // async global->LDS: global addr per-lane, LDS dest = wave-uniform base + lane*16
  __builtin_amdgcn_global_load_lds((ga_u32*)g, (ls_u32*)l, 16, 0, 0);
}

__device__ __forceinline__ unsigned short f2bf(float f) {
  unsigned int u = __float_as_uint(f);
  u += 0x7fffu + ((u >> 16) & 1u);   // RNE
  return (unsigned short)(u >> 16);
}

// ---------------- fused cast fp32 -> bf16, all 5 arrays, one launch ----------------
__global__ void castk_all(const float* __restrict__ s0, const float* __restrict__ s1,
                          const float* __restrict__ s2, const float* __restrict__ s3,
                          const float* __restrict__ s4,
                          unsigned short* __restrict__ d0, unsigned short* __restrict__ d1,
                          unsigned short* __restrict__ d2, unsigned short* __restrict__ d3,
                          unsigned short* __restrict__ d4) {
  const int id = blockIdx.x;
  const float* s; unsigned short* d; int i;
  if (id < 4096) { s = s0; d = d0; i = id * 256 + threadIdx.x; }
  else {
    const int w = (id - 4096) >> 10;
    s = (w == 0) ? s1 : (w == 1) ? s2 : (w == 2) ? s3 : s4;
    d = (w == 0) ? d1 : (w == 1) ? d2 : (w == 2) ? d3 : d4;
    i = ((id - 4096) & 1023) * 256 + threadIdx.x;
  }
  float4 v = ((const float4*)s)[i];
  ushort4 ov;
  ov.x = f2bf(v.x); ov.y = f2bf(v.y); ov.z = f2bf(v.z); ov.w = f2bf(v.w);
  ((ushort4*)d)[i] = ov;
}

// ---------------- fused QKV projection GEMM ----------------
// z=0 -> q[b,h,s,d], z=1 -> k[b,h,s,d], z=2 -> vt[b,h,d,s] (via LDS transpose)
// launch_bounds(256,2): cap 256 regs — (256,3)'s 170-reg cap forces spills on
// the 128x128 tile (needs ~228 = 164 VGPR + 64 AGPR per m97/m98).
__global__ __launch_bounds__(256, 2)
void gemm_qkv(const unsigned short* __restrict__ A,
              const unsigned short* __restrict__ W0, const unsigned short* __restrict__ W1,
              const unsigned short* __restrict__ W2,
              const float* __restrict__ b0, const float* __restrict__ b1, const float* __restrict__ b2,
              unsigned short* __restrict__ o0, unsigned short* __restrict__ o1, unsigned short* __restrict__ o2) {
  __shared__ __align__(16) unsigned short smem[128 * 136];
  unsigned short* sA = smem;          // 128*32
  unsigned short* sB = smem + 4096;   // 128*32
  const int z = blockIdx.z;
  const unsigned short* Bm = (z == 0) ? W0 : (z == 1) ? W1 : W2;
  const float* bias = (z == 0) ? b0 : (z == 1) ? b1 : b2;
  unsigned short* out = (z == 0) ? o0 : (z == 1) ? o1 : o2;

  const int m0 = blockIdx.x * 128, n0 = blockIdx.y * 128;
  const int tid = threadIdx.x;
  const int wave = tid >> 6, lane = tid & 63;
  const int quad = lane >> 4, l16 = lane & 15;
  const int wm = wave >> 1, wn = wave & 1;

  facc acc[4][4] = {};

  const int j0 = wave * 128 + lane;
  const int j1 = j0 + 64;
  const int row0 = j0 >> 2, ko0 = (j0 & 3) << 3;
  const int row1 = j1 >> 2, ko1 = (j1 & 3) << 3;
  const size_t aoff0 = (size_t)(m0 + row0) * 1024 + ko0;
  const size_t aoff1 = (size_t)(m0 + row1) * 1024 + ko1;
  const size_t boff0 = (size_t)(n0 + row0) * 1024 + ko0;
  const size_t boff1 = (size_t)(n0 + row1) * 1024 + ko1;
  unsigned short* sA0 = sA + (wave * 2 + 0) * 512;
  unsigned short* sA1 = sA + (wave * 2 + 1) * 512;
  unsigned short* sB0 = sB + (wave * 2 + 0) * 512;
  unsigned short* sB1 = sB + (wave * 2 + 1) * 512;

  for (int k0 = 0; k0 < 1024; k0 += 32) {
    gload_lds16(A + aoff0 + k0, sA0);
    gload_lds16(A + aoff1 + k0, sA1);
    gload_lds16(Bm + boff0 + k0, sB0);
    gload_lds16(Bm + boff1 + k0, sB1);
    __syncthreads();
    bfrag af[4], bf[4];
#pragma unroll
    for (int i = 0; i < 4; ++i) af[i] = *(const bfrag*)(sA + (wm * 64 + i * 16 + l16) * 32 + quad * 8);
#pragma unroll
    for (int j = 0; j < 4; ++j) bf[j] = *(const bfrag*)(sB + (wn * 64 + j * 16 + l16) * 32 + quad * 8);
#pragma unroll
    for (int i = 0; i < 4; ++i)
#pragma unroll
      for (int j = 0; j < 4; ++j)
        acc[i][j] = __builtin_amdgcn_mfma_f32_16x16x32_bf16(af[i], bf[j], acc[i][j], 0, 0, 0);
    __syncthreads();
  }

  if (z < 2) {
#pragma unroll
    for (int i = 0; i < 4; ++i)
#pragma unroll
      for (int j = 0; j < 4; ++j) {
        const int col = n0 + wn * 64 + j * 16 + l16;
        const float bv = bias[col];
        const int h = col >> 6, d = col & 63;
#pragma unroll
        for (int r = 0; r < 4; ++r) {
          const int m = m0 + wm * 64 + i * 16 + quad * 4 + r;
          const int b = m >> 10, s = m & 1023;
          out[(((size_t)(b * NHd + h) * Sd) + s) * DKd + d] = f2bf(acc[i][j][r] + bv);
        }
      }
  } else {
    unsigned short* sT = smem;  // 128 x 136 (padded)
#pragma unroll
    for (int i = 0; i < 4; ++i)
#pragma unroll
      for (int j = 0; j < 4; ++j) {
        const int col = n0 + wn * 64 + j * 16 + l16;
        const float bv = bias[col];
        const int nrow = wn * 64 + j * 16 + l16;
        const int mbase = wm * 64 + i * 16 + quad * 4;
        ushort4 pk;
        pk.x = f2bf(acc[i][j][0] + bv);
        pk.y = f2bf(acc[i][j][1] + bv);
        pk.z = f2bf(acc[i][j][2] + bv);
        pk.w = f2bf(acc[i][j][3] + bv);
        *(ushort4*)(sT + nrow * 136 + mbase) = pk;
      }
    __syncthreads();
    const int bI = m0 >> 10, s0i = m0 & 1023;
#pragma unroll
    for (int it = 0; it < 8; ++it) {
      const int c = tid + it * 256;
      const int row = c >> 4, mc = (c & 15) * 8;
      bfrag vv = *(const bfrag*)(sT + row * 136 + mc);
      const int col = n0 + row, hh = col >> 6, dd = col & 63;
      *(bfrag*)(out + (((size_t)(bI * NHd + hh) * DKd) + dd) * Sd + s0i + mc) = vv;
    }
  }
}

// ---------------- output projection GEMM: 64x128 tile, BK=64, swizzled LDS ----------------
__global__ __launch_bounds__(256, 2)
void gemm_out(const unsigned short* __restrict__ A, const unsigned short* __restrict__ Bm,
              const float* __restrict__ bias, float* __restrict__ out) {
  __shared__ __align__(16) unsigned short sA[64 * 64];    // 8 KB
  __shared__ __align__(16) unsigned short sB[128 * 64];   // 16 KB
  const int m0 = blockIdx.x * 64, n0 = blockIdx.y * 128;
  const int tid = threadIdx.x;
  const int wave = tid >> 6, lane = tid & 63;
  const int quad = lane >> 4, l16 = lane & 15;

  facc acc[8] = {};

  const int cA0 = (wave * 2 + 0) * 64 + lane;
  const int cA1 = (wave * 2 + 1) * 64 + lane;
  const int rA0 = cA0 >> 3, kA0 = ((cA0 & 7) ^ (rA0 & 7)) * 8;
  const int rA1 = cA1 >> 3, kA1 = ((cA1 & 7) ^ (rA1 & 7)) * 8;
  const size_t aoff0 = (size_t)(m0 + rA0) * 1024 + kA0;
  const size_t aoff1 = (size_t)(m0 + rA1) * 1024 + kA1;
  size_t boff[4];
#pragma unroll
  for (int i = 0; i < 4; ++i) {
    const int c = (wave * 4 + i) * 64 + lane;
    const int r = c >> 3, kk = ((c & 7) ^ (r & 7)) * 8;
    boff[i] = (size_t)(n0 + r) * 1024 + kk;
  }

  for (int k0 = 0; k0 < 1024; k0 += 64) {
    gload_lds16(A + aoff0 + k0, sA + (wave * 2 + 0) * 512);
    gload_lds16(A + aoff1 + k0, sA + (wave * 2 + 1) * 512);
#pragma unroll
    for (int i = 0; i < 4; ++i)
      gload_lds16(Bm + boff[i] + k0, sB + (wave * 4 + i) * 512);
    __syncthreads();
#pragma unroll
    for (int c2 = 0; c2 < 2; ++c2) {
      const int ko = ((c2 * 4 + quad) ^ (l16 & 7)) * 8;   // unswizzle
      bfrag af = *(const bfrag*)(sA + (wave * 16 + l16) * 64 + ko);
#pragma unroll
      for (int j = 0; j < 8; ++j) {
        bfrag bf = *(const bfrag*)(sB + (j * 16 + l16) * 64 + ko);
        acc[j] = __builtin_amdgcn_mfma_f32_16x16x32_bf16(af, bf, acc[j], 0, 0, 0);
      }
    }
    __syncthreads();
  }

#pragma unroll
  for (int j = 0; j < 8; ++j) {
    const int col = n0 + j * 16 + l16;
    const float bv = bias[col];
#pragma unroll
    for (int r = 0; r < 4; ++r) {
      const int m = m0 + wave * 16 + quad * 4 + r;
      out[(size_t)m * 1024 + col] = acc[j][r] + bv;
    }
  }
}

// ---------------- fused flash attention, split-K x2, half-tile pipeline ----------------
// grid: x = S/16 q-tiles, y = B*NH -> 4096 blocks (16 blocks/CU).
// Block = 128 threads (2 waves). Both waves own the SAME 16 q-rows; wave w
// processes key-columns [w*512, w*512+512) in 8 half-tiles of 64 cols.
// No running max (logits bounded << 88): partials combine by pure addition.
// Small register state (sacc=16, br=16) -> target 6 waves/SIMD (24 waves/CU).
__global__ __launch_bounds__(128, 6)
void attn_kernel(const unsigned short* __restrict__ q,   // [B,NH,S,DK]
                 const unsigned short* __restrict__ k,   // [B,NH,S,DK]
                 const unsigned short* __restrict__ vt,  // [B,NH,DK,S]
                 const float* __restrict__ bias,         // [B,NH,S,S]
                 unsigned short* __restrict__ o)         // [B,S,HID] bf16
{
  __shared__ __align__(16) unsigned short sP[2 * 16 * 72]; // per-wave 16x64 (+8 pad)
  __shared__ __align__(16) float sRed[64 * 20];            // wave-1 partials
  const int bh = blockIdx.y;
  const int q0 = blockIdx.x * 16;
  const int tid = threadIdx.x;
  const int wave = tid >> 6, lane = tid & 63;
  const int quad = lane >> 4, l16 = lane & 15;
  const int b = bh >> 4, h = bh & 15;

  const unsigned short* qh = q + (size_t)bh * Sd * DKd;
  const unsigned short* kh = k + (size_t)bh * Sd * DKd;
  const unsigned short* vh = vt + (size_t)bh * DKd * Sd;
  const float* bias_h = bias + (size_t)bh * Sd * Sd;
  unsigned short* sPw = sP + wave * 16 * 72;
  const int cbase = wave * 512;            // this wave's key-column range start

  bfrag qf[2];
#pragma unroll
  for (int c = 0; c < 2; ++c)
    qf[c] = *(const bfrag*)(qh + (size_t)(q0 + l16) * DKd + c * 32 + quad * 8);

  facc oacc[4] = {};
  float lsum[4] = {0.f, 0.f, 0.f, 0.f};
  const float SL2 = SCALEF * L2E;

  // bias prefetch for half-tile u (64 cols), one ahead
  float br[4][4];
  const float* bp0 = bias_h + (size_t)(q0 + quad * 4) * Sd + cbase + l16;
#pragma unroll
  for (int r = 0; r < 4; ++r)
#pragma unroll
    for (int j = 0; j < 4; ++j)
      br[r][j] = bp0[r * Sd + j * 16];

  for (int u = 0; u < 8; ++u) {
    const int c0 = cbase + u * 64;
    // ---- S = Q K^T (16 rows x 64 cols) ----
    facc sacc[4] = {};
#pragma unroll
    for (int c = 0; c < 2; ++c)
#pragma unroll
      for (int j = 0; j < 4; ++j) {
        bfrag kf = *(const bfrag*)(kh + (size_t)(c0 + j * 16 + l16) * DKd + c * 32 + quad * 8);
        sacc[j] = __builtin_amdgcn_mfma_f32_16x16x32_bf16(qf[c], kf, sacc[j], 0, 0, 0);
      }
    // ---- p = exp2(x*SCALE*log2e + bias*log2e), exact-zero mask -> 0 ----
#pragma unroll
    for (int r = 0; r < 4; ++r)
#pragma unroll
      for (int j = 0; j < 4; ++j) {
        const float x = sacc[j][r];
        float e = exp2f(fmaf(x, SL2, br[r][j] * L2E));
        e = (x == 0.0f) ? 0.0f : e;
        sacc[j][r] = e;
        lsum[r] += e;
      }
    // ---- prefetch bias for u+1 ----
    if (u < 7) {
      const float* bp = bp0 + (u + 1) * 64;
#pragma unroll
      for (int r = 0; r < 4; ++r)
#pragma unroll
        for (int j = 0; j < 4; ++j)
          br[r][j] = bp[r * Sd + j * 16];
    }
    // ---- P (C-layout) -> wave-private LDS (16x64, stride 72) ----
#pragma unroll
    for (int j = 0; j < 4; ++j)
#pragma unroll
      for (int r = 0; r < 4; ++r)
        sPw[(quad * 4 + r) * 72 + j * 16 + l16] = f2bf(sacc[j][r]);
    // ---- O += P V over the 2 32-col chunks of this half-tile ----
#pragma unroll
    for (int c2 = 0; c2 < 2; ++c2) {
      bfrag pf = *(const bfrag*)(sPw + l16 * 72 + c2 * 32 + quad * 8);
#pragma unroll
      for (int n = 0; n < 4; ++n) {
        bfrag vf = *(const bfrag*)(vh + (size_t)(n * 16 + l16) * Sd + c0 + c2 * 32 + quad * 8);
        oacc[n] = __builtin_amdgcn_mfma_f32_16x16x32_bf16(pf, vf, oacc[n], 0, 0, 0);
      }
    }
  }

  // ---- combine wave partials (pure addition: no rescale needed) ----
  if (wave == 1) {
#pragma unroll
    for (int n = 0; n < 4; ++n)
#pragma unroll
      for (int r = 0; r < 4; ++r)
        sRed[lane * 20 + n * 4 + r] = oacc[n][r];
#pragma unroll
    for (int r = 0; r < 4; ++r) sRed[lane * 20 + 16 + r] = lsum[r];
  }
  __syncthreads();
  if (wave == 0) {
#pragma unroll
    for (int n = 0; n < 4; ++n)
#pragma unroll
      for (int r = 0; r < 4; ++r)
        oacc[n][r] += sRed[lane * 20 + n * 4 + r];
#pragma unroll
    for (int r = 0; r < 4; ++r) lsum[r] += sRed[lane * 20 + 16 + r];
    // single cross-lane reduction of lsum (within 16-lane row groups)
#pragma unroll
    for (int r = 0; r < 4; ++r) {
#pragma unroll
      for (int s = 1; s < 16; s <<= 1) lsum[r] += __shfl_xor(lsum[r], s, 64);
    }
#pragma unroll
    for (int r = 0; r < 4; ++r) {
      const float rinv = 1.0f / lsum[r];
      const size_t rowo = (size_t)(b * Sd + q0 + quad * 4 + r) * Hd + h * 64;
#pragma unroll
      for (int n = 0; n < 4; ++n)
        o[rowo + n * 16 + l16] = f2bf(oacc[n][r] * rinv);
    }
  }
}

extern "C" void kernel_launch(void* const* d_in, const int* in_sizes, int n_in,
                              void* d_out, int out_size, void* d_ws, size_t ws_size,
                              hipStream_t stream) {
  const float* batch = (const float*)d_in[0];
  const float* attn_bias = (const float*)d_in[1];
  const float* Wq = (const float*)d_in[2];
  const float* bq = (const float*)d_in[3];
  const float* Wk = (const float*)d_in[4];
  const float* bk = (const float*)d_in[5];
  const float* Wv = (const float*)d_in[6];
  const float* bv = (const float*)d_in[7];
  const float* Wo = (const float*)d_in[8];
  const float* bo = (const float*)d_in[9];
  float* out = (float*)d_out;

  unsigned short* ws = (unsigned short*)d_ws;
  unsigned short* Ab  = ws;                 // 4096x1024
  unsigned short* Wqb = Ab  + 4194304;      // 1024x1024 each
  unsigned short* Wkb = Wqb + 1048576;
  unsigned short* Wvb = Wkb + 1048576;
  unsigned short* Wob = Wvb + 1048576;
  unsigned short* qb  = Wob + 1048576;      // [B,NH,S,DK]
  unsigned short* kb  = qb  + 4194304;
  unsigned short* vtb = kb  + 4194304;      // [B,NH,DK,S]
  unsigned short* ob  = vtb + 4194304;      // [B,S,HID]

  castk_all<<<8192, 256, 0, stream>>>(batch, Wq, Wk, Wv, Wo, Ab, Wqb, Wkb, Wvb, Wob);
  gemm_qkv<<<dim3(32, 8, 3), 256, 0, stream>>>(Ab, Wqb, Wkb, Wvb, bq, bk, bv, qb, kb, vtb);
  attn_kernel<<<dim3(64, 64), 128, 0, stream>>>(qb, kb, vtb, attn_bias, ob);
  gemm_out<<<dim3(64, 8), 256, 0, stream>>>(ob, Wob, bo, out);
}